// Round 20
// baseline (114.570 us; speedup 1.0000x reference)
//
#include <hip/hip_runtime.h>

// MHA: B=2, S=2048, D=1024, H=16, DK=DV=64
// Round 20: GEMMs moved to the r15 flash-proven TRIPLE-BUFFER SINGLE-BARRIER
// pipeline: per K-iter {wait vmcnt(4) -> s_barrier -> stage(t+2 into buf of
// t-1) -> compute t}. Loads get 2 iterations to land (vs 1), half the
// barriers, no lgkm drain. LDS 48KB -> still 3 blocks/CU. Trailing barrier
// before epilogue LDS reuse. Flash/prep/combine = r19 (best, 109.2us).

#define DI __device__ __forceinline__

typedef __bf16 bf16x8 __attribute__((ext_vector_type(8)));
typedef float f32x4 __attribute__((ext_vector_type(4)));
typedef unsigned short u16x8 __attribute__((ext_vector_type(8)));
typedef unsigned short u16x4 __attribute__((ext_vector_type(4)));

union U8 { u16x8 u; bf16x8 b; };
union PB { unsigned int w[4]; u16x8 u; bf16x8 b; };

typedef const __attribute__((address_space(1))) unsigned int* gas_p;
typedef __attribute__((address_space(3))) unsigned int* las_p;

DI void gload16(const unsigned short* g, unsigned short* l) {
  __builtin_amdgcn_global_load_lds((gas_p)(const void*)g, (las_p)(void*)l, 16, 0, 0);
}

#define WAIT_VM4  asm volatile("s_waitcnt vmcnt(4)" ::: "memory")
#define WAIT_VM0  asm volatile("s_waitcnt vmcnt(0)" ::: "memory")
#define BARRIER   __builtin_amdgcn_s_barrier()

DI unsigned short f2bf(float f) {            // round-to-nearest-even
  unsigned int u = __float_as_uint(f);
  u += 0x7FFFu + ((u >> 16) & 1u);
  return (unsigned short)(u >> 16);
}
DI float bf2f(unsigned short v) { return __uint_as_float((unsigned int)v << 16); }

// ---------------- kernel 0: W transpose (z<4) + x conversion (z>=4) ----------
__global__ void k_prep(
    const float* __restrict__ W0, const float* __restrict__ W1,
    const float* __restrict__ W2, const float* __restrict__ W3,
    unsigned short* __restrict__ T0, unsigned short* __restrict__ T1,
    unsigned short* __restrict__ T2, unsigned short* __restrict__ T3,
    const float* __restrict__ x, unsigned short* __restrict__ xb) {
  const int z = blockIdx.z;
  const int tx = threadIdx.x, ty = threadIdx.y;   // (32, 8)
  if (z >= 4) {
    int chunk = (z - 4) * 1024 + blockIdx.y * 32 + blockIdx.x;
    size_t i = ((size_t)chunk * 256 + ty * 32 + tx) * 4;
    float4 v = *(const float4*)(x + i);
    u16x4 o;
    o[0] = f2bf(v.x); o[1] = f2bf(v.y); o[2] = f2bf(v.z); o[3] = f2bf(v.w);
    *(u16x4*)(xb + i) = o;
    return;
  }
  const float* W = (z == 0) ? W0 : (z == 1) ? W1 : (z == 2) ? W2 : W3;
  unsigned short* T = (z == 0) ? T0 : (z == 1) ? T1 : (z == 2) ? T2 : T3;
  __shared__ unsigned short buf[32][33];
  const int k0 = blockIdx.x * 32, n0 = blockIdx.y * 32;
#pragma unroll
  for (int j = 0; j < 4; ++j) {
    int r = ty + j * 8;
    buf[r][tx] = f2bf(W[(size_t)(k0 + r) * 1024 + n0 + tx]);
  }
  __syncthreads();
#pragma unroll
  for (int j = 0; j < 4; ++j) {
    int c = ty + j * 8;
    T[(size_t)(n0 + c) * 1024 + k0 + tx] = buf[tx][c];
  }
}

// ---------------- shared GEMM main loop (BK=32, triple-buffer 1-barrier) ------
DI void stage_gemm(const unsigned short* __restrict__ src, unsigned short* dst,
                   int row0, int k0, int tid, int wid) {
#pragma unroll
  for (int i = 0; i < 2; ++i) {
    int T = i * 256 + tid;
    int row = T >> 2, ch = T & 3;
    int sch = ch ^ (row & 3);
    gload16(&src[(size_t)(row0 + row) * 1024 + k0 + sch * 8],
            &dst[(i * 256 + wid * 64) * 8]);
  }
}

DI void gemm_main(const unsigned short* __restrict__ A,
                  const unsigned short* __restrict__ Bm,
                  unsigned short* As, unsigned short* Bs,
                  int m0, int n0, f32x4 acc[4][4]) {
  const int tid = threadIdx.x;
  const int lane = tid & 63, wid = tid >> 6;
  const int wr = wid >> 1, wc = wid & 1;
  const int g = lane >> 4, lq = lane & 15;

  stage_gemm(A, As, m0, 0, tid, wid);
  stage_gemm(Bm, Bs, n0, 0, tid, wid);
  stage_gemm(A, As + 4096, m0, 32, tid, wid);
  stage_gemm(Bm, Bs + 4096, n0, 32, tid, wid);
  int bi = 0;
  for (int k0 = 0; k0 < 1024; k0 += 32) {
    if (k0 + 32 < 1024) WAIT_VM4; else WAIT_VM0;   // own tile-k0 loads landed
    BARRIER;                                       // all waves: k0 ready, k0-32 computed
    if (k0 + 64 < 1024) {
      int nb = bi + 2; if (nb >= 3) nb -= 3;
      stage_gemm(A, As + nb * 4096, m0, k0 + 64, tid, wid);
      stage_gemm(Bm, Bs + nb * 4096, n0, k0 + 64, tid, wid);
    }
    const unsigned short* Ab = As + bi * 4096;
    const unsigned short* Bb = Bs + bi * 4096;
    U8 af[4], bfr[4];
#pragma unroll
    for (int f = 0; f < 4; ++f) {
      af[f].u  = *(const u16x8*)&Ab[(wr * 64 + f * 16 + lq) * 32 + ((g ^ (lq & 3)) * 8)];
      bfr[f].u = *(const u16x8*)&Bb[(wc * 64 + f * 16 + lq) * 32 + ((g ^ (lq & 3)) * 8)];
    }
#pragma unroll
    for (int i = 0; i < 4; ++i)
#pragma unroll
      for (int j = 0; j < 4; ++j)
        acc[i][j] = __builtin_amdgcn_mfma_f32_16x16x32_bf16(af[i].b, bfr[j].b,
                                                            acc[i][j], 0, 0, 0);
    ++bi; if (bi >= 3) bi = 0;
  }
  BARRIER;   // all waves done computing before caller reuses LDS
}

// ---------------- kernel 1: QKV projection (LDS-restaged epilogue) ----------
__global__ __launch_bounds__(256) void k_gemm_qkv(
    const unsigned short* __restrict__ xb,
    const unsigned short* __restrict__ Wqt, const unsigned short* __restrict__ Wkt,
    const unsigned short* __restrict__ Wvt,
    const float* __restrict__ bq, const float* __restrict__ bk,
    const float* __restrict__ bv,
    unsigned short* __restrict__ Qo, unsigned short* __restrict__ Ko,
    unsigned short* __restrict__ Vto) {
  __shared__ unsigned short Sh[24576];   // 48KB: A 3-buf (12288) + B 3-buf; epilogue reuses first 17408
  unsigned short* As = Sh;
  unsigned short* Bs = Sh + 12288;
  const int z = blockIdx.z;
  const unsigned short* Bm = (z == 0) ? Wqt : (z == 1) ? Wkt : Wvt;
  const float* bias = (z == 0) ? bq : (z == 1) ? bk : bv;

  f32x4 acc[4][4];
#pragma unroll
  for (int i = 0; i < 4; ++i)
#pragma unroll
    for (int j = 0; j < 4; ++j) acc[i][j] = f32x4{0.f, 0.f, 0.f, 0.f};

  const int m0 = blockIdx.x * 128, n0 = blockIdx.y * 128;
  gemm_main(xb, Bm, As, Bs, m0, n0, acc);

  const int tid = threadIdx.x;
  const int lane = tid & 63, wid = tid >> 6;
  const int wr = wid >> 1, wc = wid & 1;
  const int g = lane >> 4, lq = lane & 15;
  const int bb = m0 >> 11;   // batch (128-row tile within one batch)

#pragma unroll
  for (int j = 0; j < 4; ++j) {
    int col = wc * 64 + j * 16 + lq;
    float bv_ = bias[n0 + col];
#pragma unroll
    for (int i = 0; i < 4; ++i)
#pragma unroll
      for (int r = 0; r < 4; ++r) {
        int row = wr * 64 + i * 16 + g * 4 + r;
        Sh[row * 136 + col] = f2bf(acc[i][j][r] + bv_);
      }
  }
  __syncthreads();

  if (z < 2) {
    unsigned short* dstQK = (z == 0) ? Qo : Ko;
    const int ch = tid & 15, sb = tid >> 4;
#pragma unroll
    for (int it = 0; it < 8; ++it) {
      int s = sb + it * 16;
      u16x8 v = *(const u16x8*)&Sh[s * 136 + ch * 8];
      int gcol = n0 + ch * 8;
      int hh = gcol >> 6, dd = gcol & 63;
      int sr = (m0 + s) & 2047;
      *(u16x8*)&dstQK[(((size_t)(bb * 16 + hh)) * 2048 + sr) * 64 + dd] = v;
    }
  } else {
    const int d = tid & 127, hf = tid >> 7;
    int gcol = n0 + d;
    int hh = gcol >> 6, dd = gcol & 63;
    size_t vrow = ((size_t)(bb * 16 + hh)) * 64 + dd;
#pragma unroll
    for (int it = 0; it < 8; ++it) {
      int s0 = (hf + it * 2) * 8;
      u16x8 vv;
#pragma unroll
      for (int e = 0; e < 8; ++e) vv[e] = Sh[(s0 + e) * 136 + d];
      *(u16x8*)&Vto[vrow * 2048 + (m0 & 2047) + s0] = vv;
    }
  }
}

// ---------------- kernel 3: output projection (fp32 out + bias) ----------------
__global__ __launch_bounds__(256) void k_gemm_out(
    const unsigned short* __restrict__ Ob, const unsigned short* __restrict__ Wot,
    const float* __restrict__ bo, float* __restrict__ out) {
  __shared__ unsigned short As[3 * 4096];
  __shared__ unsigned short Bs[3 * 4096];
  f32x4 acc[4][4];
#pragma unroll
  for (int i = 0; i < 4; ++i)
#pragma unroll
    for (int j = 0; j < 4; ++j) acc[i][j] = f32x4{0.f, 0.f, 0.f, 0.f};

  const int m0 = blockIdx.x * 128, n0 = blockIdx.y * 128;
  gemm_main(Ob, Wot, As, Bs, m0, n0, acc);

  const int lane = threadIdx.x & 63, wid = threadIdx.x >> 6;
  const int wr = wid >> 1, wc = wid & 1;
  const int g = lane >> 4, lq = lane & 15;
#pragma unroll
  for (int j = 0; j < 4; ++j) {
    int col = n0 + wc * 64 + j * 16 + lq;
    float bv_ = bo[col];
#pragma unroll
    for (int i = 0; i < 4; ++i)
#pragma unroll
      for (int r = 0; r < 4; ++r) {
        int row = m0 + wr * 64 + i * 16 + g * 4 + r;
        out[(size_t)row * 1024 + col] = acc[i][j][r] + bv_;
      }
  }
}

// ---------------- kernel 2: flash attention v15 (r19 form, unchanged) ---------
template<bool MASKED>
DI void ptile(f32x4 sacc[4], f32x4& lacc, unsigned int pk[4][2],
              int qrow, int kk0, int g) {
  const float SC = 0.18033688011112042f;   // 0.125 * log2(e)
#pragma unroll
  for (int c = 0; c < 4; ++c) {
#pragma unroll
    for (int r = 0; r < 4; ++r) {
      float sv = fabsf(sacc[c][r]) * SC;
      if (MASKED) {
        int k = kk0 + g * 8 + r + 4 * (c & 1) + 32 * (c >> 1);
        sv = (k <= qrow) ? sv : -1e30f;
      }
      float p = exp2f(sv);
      sacc[c][r] = p;
      lacc[r] += p;
    }
    asm("v_cvt_pk_bf16_f32 %0, %1, %2"
        : "=v"(pk[c][0]) : "v"(sacc[c][0]), "v"(sacc[c][1]));
    asm("v_cvt_pk_bf16_f32 %0, %1, %2"
        : "=v"(pk[c][1]) : "v"(sacc[c][2]), "v"(sacc[c][3]));
  }
}

DI void flash_dual(bool complete, int qblk, int t0, int t1, int slot,
                   const unsigned short* __restrict__ Q,
                   const unsigned short* __restrict__ Km,
                   const unsigned short* __restrict__ Vt,
                   unsigned short* __restrict__ O,
                   unsigned short* __restrict__ Pp, float* __restrict__ Lp,
                   unsigned short* Ks0, unsigned short* Vs0,
                   size_t qkbase, size_t vbase, int b, int h,
                   int tid, int wid, int g, int lq) {
  const int lrowA = wid * 32 + lq, lrowB = lrowA + 16;
  const int qrowA = qblk * 128 + lrowA, qrowB = qblk * 128 + lrowB;
  const int diag0 = 2 * qblk;

  auto stage = [&](int bf, int t) {           // 4 gload16/thread
    const int kk0 = t * 64;
#pragma unroll
    for (int i = 0; i < 2; ++i) {
      int T = i * 256 + tid;
      int row = T >> 3, ch = T & 7;
      int sch = ch ^ (row & 7);
      gload16(&Km[qkbase + (size_t)(kk0 + row) * 64 + sch * 8],
              Ks0 + bf * 4096 + (i * 2048 + wid * 512));
      gload16(&Vt[vbase + (size_t)row * 2048 + kk0 + sch * 8],
              Vs0 + bf * 4096 + (i * 2048 + wid * 512));
    }
  };

  U8 aqA0, aqA1, aqB0, aqB1;
  {
    const unsigned short* qp = &Q[qkbase + (size_t)qrowA * 64 + g * 8];
    aqA0.u = *(const u16x8*)qp;
    aqA1.u = *(const u16x8*)(qp + 32);
    const unsigned short* qp2 = &Q[qkbase + (size_t)qrowB * 64 + g * 8];
    aqB0.u = *(const u16x8*)qp2;
    aqB1.u = *(const u16x8*)(qp2 + 32);
  }
  f32x4 laccA = f32x4{0.f, 0.f, 0.f, 0.f}, laccB = f32x4{0.f, 0.f, 0.f, 0.f};
  f32x4 oaccA[4], oaccB[4];
#pragma unroll
  for (int c = 0; c < 4; ++c) {
    oaccA[c] = f32x4{0.f, 0.f, 0.f, 0.f};
    oaccB[c] = f32x4{0.f, 0.f, 0.f, 0.f};
  }

  const int rbase = (lq >> 2) * 8 + (lq & 3);

  stage(0, t0);
  if (t0 + 1 < t1) stage(1, t0 + 1);
  int bi = 0;
  for (int t = t0; t < t1; ++t) {
    if (t + 1 < t1) WAIT_VM4; else WAIT_VM0;
    BARRIER;
    if (t + 2 < t1) {
      int nb = bi + 2; if (nb >= 3) nb -= 3;
      stage(nb, t + 2);
    }
    const unsigned short* Kb = Ks0 + bi * 4096;
    const unsigned short* Vb = Vs0 + bi * 4096;
    const int kk0 = t * 64;
    f32x4 saccA[4], saccB[4];
    __builtin_amdgcn_s_setprio(1);
#pragma unroll
    for (int c = 0; c < 4; ++c) {
      int row = rbase + 4 * (c & 1) + 32 * (c >> 1);
      int r7 = row & 7;
      U8 kf0, kf1;
      kf0.u = *(const u16x8*)&Kb[row * 64 + ((g ^ r7) * 8)];
      kf1.u = *(const u16x8*)&Kb[row * 64 + (((4 + g) ^ r7) * 8)];
      saccA[c] = __builtin_amdgcn_mfma_f32_16x16x32_bf16(kf0.b, aqA0.b,
                                                         f32x4{0.f, 0.f, 0.f, 0.f}, 0, 0, 0);
      saccA[c] = __builtin_amdgcn_mfma_f32_16x16x32_bf16(kf1.b, aqA1.b, saccA[c], 0, 0, 0);
      saccB[c] = __builtin_amdgcn_mfma_f32_16x16x32_bf16(kf0.b, aqB0.b,
                                                         f32x4{0.f, 0.f, 0.f, 0.f}, 0, 0, 0);
      saccB[c] = __builtin_amdgcn_mfma_f32_16x16x32_bf16(kf1.b, aqB1.b, saccB[c], 0, 0, 0);
    }
    __builtin_amdgcn_s_setprio(0);
    unsigned int pkA[4][2], pkB[4][2];
    if (t >= diag0) {
      ptile<true>(saccA, laccA, pkA, qrowA, kk0, g);
      ptile<true>(saccB, laccB, pkB, qrowB, kk0, g);
    } else {
      ptile<false>(saccA, laccA, pkA, qrowA, kk0, g);
      ptile<false>(saccB, laccB, pkB, qrowB, kk0, g);
    }
    __builtin_amdgcn_s_setprio(1);
#pragma unroll
    for (int hh = 0; hh < 2; ++hh) {
      PB pbA, pbB;
      pbA.w[0] = pkA[hh * 2 + 0][0]; pbA.w[1] = pkA[hh * 2 + 0][1];
      pbA.w[2] = pkA[hh * 2 + 1][0]; pbA.w[3] = pkA[hh * 2 + 1][1];
      pbB.w[0] = pkB[hh * 2 + 0][0]; pbB.w[1] = pkB[hh * 2 + 0][1];
      pbB.w[2] = pkB[hh * 2 + 1][0]; pbB.w[3] = pkB[hh * 2 + 1][1];
#pragma unroll
      for (int c = 0; c < 4; ++c) {
        U8 vf;
        vf.u = *(const u16x8*)&Vb[(c * 16 + lq) * 64 + (((hh * 4 + g) ^ (lq & 7)) * 8)];
        oaccA[c] = __builtin_amdgcn_mfma_f32_16x16x32_bf16(vf.b, pbA.b, oaccA[c], 0, 0, 0);
        oaccB[c] = __builtin_amdgcn_mfma_f32_16x16x32_bf16(vf.b, pbB.b, oaccB[c], 0, 0, 0);
      }
    }
    __builtin_amdgcn_s_setprio(0);
    ++bi; if (bi >= 3) bi = 0;
  }

  float lsA = (laccA[0] + laccA[1]) + (laccA[2] + laccA[3]);
  lsA += __shfl_xor(lsA, 16, 64);
  lsA += __shfl_xor(lsA, 32, 64);
  float lsB = (laccB[0] + laccB[1]) + (laccB[2] + laccB[3]);
  lsB += __shfl_xor(lsB, 16, 64);
  lsB += __shfl_xor(lsB, 32, 64);
  if (complete) {
    float invA = 1.0f / lsA, invB = 1.0f / lsB;
#pragma unroll
    for (int c = 0; c < 4; ++c) {
      u16x4 ovA, ovB;
#pragma unroll
      for (int r2 = 0; r2 < 4; ++r2) {
        ovA[r2] = f2bf(oaccA[c][r2] * invA);
        ovB[r2] = f2bf(oaccB[c][r2] * invB);
      }
      *(u16x4*)&O[((size_t)(b * 2048 + qrowA)) * 1024 + h * 64 + c * 16 + g * 4] = ovA;
      *(u16x4*)&O[((size_t)(b * 2048 + qrowB)) * 1024 + h * 64 + c * 16 + g * 4] = ovB;
    }
  } else {
    if (g == 0) {
      Lp[slot * 128 + lrowA] = lsA;
      Lp[slot * 128 + lrowB] = lsB;
    }
    size_t pbase = (size_t)slot * 8192;
#pragma unroll
    for (int c = 0; c < 4; ++c) {
      u16x4 ovA, ovB;
#pragma unroll
      for (int r2 = 0; r2 < 4; ++r2) {
        ovA[r2] = f2bf(oaccA[c][r2]);
        ovB[r2] = f2bf(oaccB[c][r2]);
      }
      *(u16x4*)&Pp[pbase + lrowA * 64 + c * 16 + g * 4] = ovA;
      *(u16x4*)&Pp[pbase + lrowB * 64 + c * 16 + g * 4] = ovB;
    }
  }
  WAIT_VM0;
  BARRIER;
}

__global__ __launch_bounds__(256) void k_flash(
    const unsigned short* __restrict__ Q, const unsigned short* __restrict__ Km,
    const unsigned short* __restrict__ Vt, unsigned short* __restrict__ O,
    unsigned short* __restrict__ Pp, float* __restrict__ Lp) {
  __shared__ unsigned short Ks[3 * 4096];
  __shared__ unsigned short Vs[3 * 4096];
  const int tid = threadIdx.x;
  const int lane = tid & 63, wid = tid >> 6;
  const int g = lane >> 4, lq = lane & 15;
  const int bid = blockIdx.x;               // 512 blocks
  const int xcd = bid & 7, idx = bid >> 3;  // 64 per XCD
  const int bh = xcd * 4 + (idx >> 4);      // 4 bh per XCD
  const int rr = idx & 15;
  const int p = rr >> 1, sp = rr & 1;
  const int mp = 15 - p;
  const int b = bh >> 4, h = bh & 15;
  const size_t qkbase = (size_t)bh * 2048 * 64;
  const size_t vbase = (size_t)bh * 64 * 2048;

  if (sp == 0) {
    flash_dual(true, p, 0, 2 * p + 2, 0, Q, Km, Vt, O, Pp, Lp,
               Ks, Vs, qkbase, vbase, b, h, tid, wid, g, lq);
    flash_dual(false, mp, 0, 15 - 2 * p, (bh * 8 + p) * 2 + 0, Q, Km, Vt, O, Pp, Lp,
               Ks, Vs, qkbase, vbase, b, h, tid, wid, g, lq);
  } else {
    flash_dual(false, mp, 15 - 2 * p, 32 - 2 * p, (bh * 8 + p) * 2 + 1, Q, Km, Vt, O, Pp, Lp,
               Ks, Vs, qkbase, vbase, b, h, tid, wid, g, lq);
  }
}

// ---------------- kernel 2b: combine mirror partials (128-row slots) ---------
__global__ __launch_bounds__(256) void k_combine(
    const unsigned short* __restrict__ Pp, const float* __restrict__ Lp,
    unsigned short* __restrict__ O) {
  int gid = blockIdx.x * 256 + threadIdx.x;   // 524288 threads
  int dv4 = gid & 15;
  int q   = (gid >> 4) & 127;
  int pi  = (gid >> 11) & 7;
  int bh  = gid >> 14;
  int slot0 = (bh * 8 + pi) * 2;
  size_t base = (size_t)slot0 * 8192 + q * 64 + dv4 * 4;
  u16x4 a = *(const u16x4*)&Pp[base];
  u16x4 c = *(const u16x4*)&Pp[base + 8192];
  float l = Lp[slot0 * 128 + q] + Lp[(slot0 + 1) * 128 + q];
  float inv = 1.0f / l;
  u16x4 o;
#pragma unroll
  for (int r = 0; r < 4; ++r) o[r] = f2bf((bf2f(a[r]) + bf2f(c[r])) * inv);
  int b = bh >> 4, h = bh & 15;
  int srow = (15 - pi) * 128 + q;
  *(u16x4*)&O[((size_t)(b * 2048 + srow)) * 1024 + h * 64 + dv4 * 4] = o;
}

// ---------------- launch ----------------
extern "C" void kernel_launch(void* const* d_in, const int* in_sizes, int n_in,
                              void* d_out, int out_size, void* d_ws, size_t ws_size,
                              hipStream_t stream) {
  const float* x  = (const float*)d_in[0];
  const float* Wq = (const float*)d_in[1];
  const float* bq = (const float*)d_in[2];
  const float* Wk = (const float*)d_in[3];
  const float* bk = (const float*)d_in[4];
  const float* Wv = (const float*)d_in[5];
  const float* bv = (const float*)d_in[6];
  const float* Wo = (const float*)d_in[7];
  const float* bo = (const float*)d_in[8];
  float* out = (float*)d_out;

  char* ws = (char*)d_ws;
  const size_t MB = 1024 * 1024;
  unsigned short* xb   = (unsigned short*)(ws + 0 * MB);   // 8 MB (dead after qkv)
  unsigned short* Wqt  = (unsigned short*)(ws + 8 * MB);   // 2 MB (dead after qkv)
  unsigned short* Wkt  = (unsigned short*)(ws + 10 * MB);  // 2 MB
  unsigned short* Wvt  = (unsigned short*)(ws + 12 * MB);  // 2 MB
  unsigned short* Wot  = (unsigned short*)(ws + 14 * MB);  // 2 MB (used by out-proj)
  unsigned short* Qws  = (unsigned short*)(ws + 16 * MB);  // 8 MB
  unsigned short* Kws  = (unsigned short*)(ws + 24 * MB);  // 8 MB
  unsigned short* Vtws = (unsigned short*)(ws + 32 * MB);  // 8 MB
  unsigned short* Ows  = (unsigned short*)(ws + 40 * MB);  // 8 MB
  unsigned short* Pp   = (unsigned short*)(ws + 0 * MB);   // 8 MB, overlays xb
  float*          Lp   = (float*)(ws + 8 * MB);            // 256 KB, overlays Wqt

  k_prep<<<dim3(32, 32, 8), dim3(32, 8), 0, stream>>>(Wq, Wk, Wv, Wo,
                                                      Wqt, Wkt, Wvt, Wot, x, xb);
  k_gemm_qkv<<<dim3(32, 8, 3), 256, 0, stream>>>(xb, Wqt, Wkt, Wvt, bq, bk, bv,
                                                 Qws, Kws, Vtws);
  k_flash<<<512, 256, 0, stream>>>(Qws, Kws, Vtws, Ows, Pp, Lp);
  k_combine<<<2048, 256, 0, stream>>>(Pp, Lp, Ows);
  k_gemm_out<<<dim3(32, 8), 256, 0, stream>>>(Ows, Wot, bo, out);
}

// Round 21
// 109.233 us; speedup vs baseline: 1.0489x; 1.0489x over previous
//
#include <hip/hip_runtime.h>

// MHA: B=2, S=2048, D=1024, H=16, DK=DV=64
// Round 21: REVERT r20 (triple-buffer GEMM: asm-pinned scheduling beat by the
// compiler's own 2-barrier dbuf; 114.6 vs 109.2). Restore r19/r17 verbatim --
// the twice-reproduced best (109.2-109.5us):
//  - k_prep: W transpose + x->bf16 merged
//  - QKV: 3-launch 128x128 BK=32 gload_lds dbuf GEMM, LDS-restaged epilogue
//  - flash: 512x256, dual-group 32q/wave, split-pair uniform, sigma
//    zero-shuffle refrag, fixed-m exp2 softmax, triple-buffer single-barrier
//  - k_combine: mirror partial merge;  out-proj: same GEMM, fp32 epilogue
// GEMM variant ledger (all regressed): BK=64 (r13), fused QKV (r16),
// triple-buffer (r20). Flash ledger: 45.4-45.6us across 5 structures.

#define DI __device__ __forceinline__

typedef __bf16 bf16x8 __attribute__((ext_vector_type(8)));
typedef float f32x4 __attribute__((ext_vector_type(4)));
typedef unsigned short u16x8 __attribute__((ext_vector_type(8)));
typedef unsigned short u16x4 __attribute__((ext_vector_type(4)));

union U8 { u16x8 u; bf16x8 b; };
union PB { unsigned int w[4]; u16x8 u; bf16x8 b; };

typedef const __attribute__((address_space(1))) unsigned int* gas_p;
typedef __attribute__((address_space(3))) unsigned int* las_p;

DI void gload16(const unsigned short* g, unsigned short* l) {
  __builtin_amdgcn_global_load_lds((gas_p)(const void*)g, (las_p)(void*)l, 16, 0, 0);
}

#define WAIT_VM4  asm volatile("s_waitcnt vmcnt(4)" ::: "memory")
#define WAIT_VM0  asm volatile("s_waitcnt vmcnt(0)" ::: "memory")
#define BARRIER   __builtin_amdgcn_s_barrier()

DI unsigned short f2bf(float f) {            // round-to-nearest-even
  unsigned int u = __float_as_uint(f);
  u += 0x7FFFu + ((u >> 16) & 1u);
  return (unsigned short)(u >> 16);
}
DI float bf2f(unsigned short v) { return __uint_as_float((unsigned int)v << 16); }

// ---------------- kernel 0: W transpose (z<4) + x conversion (z>=4) ----------
__global__ void k_prep(
    const float* __restrict__ W0, const float* __restrict__ W1,
    const float* __restrict__ W2, const float* __restrict__ W3,
    unsigned short* __restrict__ T0, unsigned short* __restrict__ T1,
    unsigned short* __restrict__ T2, unsigned short* __restrict__ T3,
    const float* __restrict__ x, unsigned short* __restrict__ xb) {
  const int z = blockIdx.z;
  const int tx = threadIdx.x, ty = threadIdx.y;   // (32, 8)
  if (z >= 4) {
    int chunk = (z - 4) * 1024 + blockIdx.y * 32 + blockIdx.x;
    size_t i = ((size_t)chunk * 256 + ty * 32 + tx) * 4;
    float4 v = *(const float4*)(x + i);
    u16x4 o;
    o[0] = f2bf(v.x); o[1] = f2bf(v.y); o[2] = f2bf(v.z); o[3] = f2bf(v.w);
    *(u16x4*)(xb + i) = o;
    return;
  }
  const float* W = (z == 0) ? W0 : (z == 1) ? W1 : (z == 2) ? W2 : W3;
  unsigned short* T = (z == 0) ? T0 : (z == 1) ? T1 : (z == 2) ? T2 : T3;
  __shared__ unsigned short buf[32][33];
  const int k0 = blockIdx.x * 32, n0 = blockIdx.y * 32;
#pragma unroll
  for (int j = 0; j < 4; ++j) {
    int r = ty + j * 8;
    buf[r][tx] = f2bf(W[(size_t)(k0 + r) * 1024 + n0 + tx]);
  }
  __syncthreads();
#pragma unroll
  for (int j = 0; j < 4; ++j) {
    int c = ty + j * 8;
    T[(size_t)(n0 + c) * 1024 + k0 + tx] = buf[tx][c];
  }
}

// ---------------- shared GEMM main loop (BK=32, gload_lds + dbuf) ------------
DI void stage_gemm(const unsigned short* __restrict__ src, unsigned short* dst,
                   int row0, int k0, int tid, int wid) {
#pragma unroll
  for (int i = 0; i < 2; ++i) {
    int T = i * 256 + tid;
    int row = T >> 2, ch = T & 3;
    int sch = ch ^ (row & 3);
    gload16(&src[(size_t)(row0 + row) * 1024 + k0 + sch * 8],
            &dst[(i * 256 + wid * 64) * 8]);
  }
}

DI void gemm_main(const unsigned short* __restrict__ A,
                  const unsigned short* __restrict__ Bm,
                  unsigned short* As, unsigned short* Bs,
                  int m0, int n0, f32x4 acc[4][4]) {
  const int tid = threadIdx.x;
  const int lane = tid & 63, wid = tid >> 6;
  const int wr = wid >> 1, wc = wid & 1;
  const int g = lane >> 4, lq = lane & 15;

  stage_gemm(A, As, m0, 0, tid, wid);
  stage_gemm(Bm, Bs, n0, 0, tid, wid);
  __syncthreads();
  int buf = 0;
  for (int k0 = 0; k0 < 1024; k0 += 32) {
    if (k0 + 32 < 1024) {
      stage_gemm(A, As + (buf ^ 1) * 4096, m0, k0 + 32, tid, wid);
      stage_gemm(Bm, Bs + (buf ^ 1) * 4096, n0, k0 + 32, tid, wid);
    }
    const unsigned short* Ab = As + buf * 4096;
    const unsigned short* Bb = Bs + buf * 4096;
    U8 af[4], bfr[4];
#pragma unroll
    for (int f = 0; f < 4; ++f) {
      af[f].u  = *(const u16x8*)&Ab[(wr * 64 + f * 16 + lq) * 32 + ((g ^ (lq & 3)) * 8)];
      bfr[f].u = *(const u16x8*)&Bb[(wc * 64 + f * 16 + lq) * 32 + ((g ^ (lq & 3)) * 8)];
    }
#pragma unroll
    for (int i = 0; i < 4; ++i)
#pragma unroll
      for (int j = 0; j < 4; ++j)
        acc[i][j] = __builtin_amdgcn_mfma_f32_16x16x32_bf16(af[i].b, bfr[j].b,
                                                            acc[i][j], 0, 0, 0);
    __syncthreads();
    buf ^= 1;
  }
}

// ---------------- kernel 1: QKV projection (LDS-restaged epilogue) ----------
__global__ __launch_bounds__(256) void k_gemm_qkv(
    const unsigned short* __restrict__ xb,
    const unsigned short* __restrict__ Wqt, const unsigned short* __restrict__ Wkt,
    const unsigned short* __restrict__ Wvt,
    const float* __restrict__ bq, const float* __restrict__ bk,
    const float* __restrict__ bv,
    unsigned short* __restrict__ Qo, unsigned short* __restrict__ Ko,
    unsigned short* __restrict__ Vto) {
  __shared__ unsigned short Sh[128 * 136];   // dbuf (16384) + epilogue tile
  unsigned short* As = Sh;
  unsigned short* Bs = Sh + 8192;
  const int z = blockIdx.z;
  const unsigned short* Bm = (z == 0) ? Wqt : (z == 1) ? Wkt : Wvt;
  const float* bias = (z == 0) ? bq : (z == 1) ? bk : bv;

  f32x4 acc[4][4];
#pragma unroll
  for (int i = 0; i < 4; ++i)
#pragma unroll
    for (int j = 0; j < 4; ++j) acc[i][j] = f32x4{0.f, 0.f, 0.f, 0.f};

  const int m0 = blockIdx.x * 128, n0 = blockIdx.y * 128;
  gemm_main(xb, Bm, As, Bs, m0, n0, acc);

  const int tid = threadIdx.x;
  const int lane = tid & 63, wid = tid >> 6;
  const int wr = wid >> 1, wc = wid & 1;
  const int g = lane >> 4, lq = lane & 15;
  const int bb = m0 >> 11;   // batch (128-row tile within one batch)

#pragma unroll
  for (int j = 0; j < 4; ++j) {
    int col = wc * 64 + j * 16 + lq;
    float bv_ = bias[n0 + col];
#pragma unroll
    for (int i = 0; i < 4; ++i)
#pragma unroll
      for (int r = 0; r < 4; ++r) {
        int row = wr * 64 + i * 16 + g * 4 + r;
        Sh[row * 136 + col] = f2bf(acc[i][j][r] + bv_);
      }
  }
  __syncthreads();

  if (z < 2) {
    unsigned short* dstQK = (z == 0) ? Qo : Ko;
    const int ch = tid & 15, sb = tid >> 4;
#pragma unroll
    for (int it = 0; it < 8; ++it) {
      int s = sb + it * 16;
      u16x8 v = *(const u16x8*)&Sh[s * 136 + ch * 8];
      int gcol = n0 + ch * 8;
      int hh = gcol >> 6, dd = gcol & 63;
      int sr = (m0 + s) & 2047;
      *(u16x8*)&dstQK[(((size_t)(bb * 16 + hh)) * 2048 + sr) * 64 + dd] = v;
    }
  } else {
    const int d = tid & 127, hf = tid >> 7;
    int gcol = n0 + d;
    int hh = gcol >> 6, dd = gcol & 63;
    size_t vrow = ((size_t)(bb * 16 + hh)) * 64 + dd;
#pragma unroll
    for (int it = 0; it < 8; ++it) {
      int s0 = (hf + it * 2) * 8;
      u16x8 vv;
#pragma unroll
      for (int e = 0; e < 8; ++e) vv[e] = Sh[(s0 + e) * 136 + d];
      *(u16x8*)&Vto[vrow * 2048 + (m0 & 2047) + s0] = vv;
    }
  }
}

// ---------------- kernel 3: output projection (fp32 out + bias) ----------------
__global__ __launch_bounds__(256) void k_gemm_out(
    const unsigned short* __restrict__ Ob, const unsigned short* __restrict__ Wot,
    const float* __restrict__ bo, float* __restrict__ out) {
  __shared__ unsigned short As[2 * 4096];
  __shared__ unsigned short Bs[2 * 4096];
  f32x4 acc[4][4];
#pragma unroll
  for (int i = 0; i < 4; ++i)
#pragma unroll
    for (int j = 0; j < 4; ++j) acc[i][j] = f32x4{0.f, 0.f, 0.f, 0.f};

  const int m0 = blockIdx.x * 128, n0 = blockIdx.y * 128;
  gemm_main(Ob, Wot, As, Bs, m0, n0, acc);

  const int lane = threadIdx.x & 63, wid = threadIdx.x >> 6;
  const int wr = wid >> 1, wc = wid & 1;
  const int g = lane >> 4, lq = lane & 15;
#pragma unroll
  for (int j = 0; j < 4; ++j) {
    int col = n0 + wc * 64 + j * 16 + lq;
    float bv_ = bo[col];
#pragma unroll
    for (int i = 0; i < 4; ++i)
#pragma unroll
      for (int r = 0; r < 4; ++r) {
        int row = m0 + wr * 64 + i * 16 + g * 4 + r;
        out[(size_t)row * 1024 + col] = acc[i][j][r] + bv_;
      }
  }
}

// ---------------- kernel 2: flash attention v15 (r17/r19 form) ----------------
template<bool MASKED>
DI void ptile(f32x4 sacc[4], f32x4& lacc, unsigned int pk[4][2],
              int qrow, int kk0, int g) {
  const float SC = 0.18033688011112042f;   // 0.125 * log2(e)
#pragma unroll
  for (int c = 0; c < 4; ++c) {
#pragma unroll
    for (int r = 0; r < 4; ++r) {
      float sv = fabsf(sacc[c][r]) * SC;
      if (MASKED) {
        int k = kk0 + g * 8 + r + 4 * (c & 1) + 32 * (c >> 1);
        sv = (k <= qrow) ? sv : -1e30f;
      }
      float p = exp2f(sv);
      sacc[c][r] = p;
      lacc[r] += p;
    }
    asm("v_cvt_pk_bf16_f32 %0, %1, %2"
        : "=v"(pk[c][0]) : "v"(sacc[c][0]), "v"(sacc[c][1]));
    asm("v_cvt_pk_bf16_f32 %0, %1, %2"
        : "=v"(pk[c][1]) : "v"(sacc[c][2]), "v"(sacc[c][3]));
  }
}

DI void flash_dual(bool complete, int qblk, int t0, int t1, int slot,
                   const unsigned short* __restrict__ Q,
                   const unsigned short* __restrict__ Km,
                   const unsigned short* __restrict__ Vt,
                   unsigned short* __restrict__ O,
                   unsigned short* __restrict__ Pp, float* __restrict__ Lp,
                   unsigned short* Ks0, unsigned short* Vs0,
                   size_t qkbase, size_t vbase, int b, int h,
                   int tid, int wid, int g, int lq) {
  const int lrowA = wid * 32 + lq, lrowB = lrowA + 16;
  const int qrowA = qblk * 128 + lrowA, qrowB = qblk * 128 + lrowB;
  const int diag0 = 2 * qblk;

  auto stage = [&](int bf, int t) {           // 4 gload16/thread
    const int kk0 = t * 64;
#pragma unroll
    for (int i = 0; i < 2; ++i) {
      int T = i * 256 + tid;
      int row = T >> 3, ch = T & 7;
      int sch = ch ^ (row & 7);
      gload16(&Km[qkbase + (size_t)(kk0 + row) * 64 + sch * 8],
              Ks0 + bf * 4096 + (i * 2048 + wid * 512));
      gload16(&Vt[vbase + (size_t)row * 2048 + kk0 + sch * 8],
              Vs0 + bf * 4096 + (i * 2048 + wid * 512));
    }
  };

  U8 aqA0, aqA1, aqB0, aqB1;
  {
    const unsigned short* qp = &Q[qkbase + (size_t)qrowA * 64 + g * 8];
    aqA0.u = *(const u16x8*)qp;
    aqA1.u = *(const u16x8*)(qp + 32);
    const unsigned short* qp2 = &Q[qkbase + (size_t)qrowB * 64 + g * 8];
    aqB0.u = *(const u16x8*)qp2;
    aqB1.u = *(const u16x8*)(qp2 + 32);
  }
  f32x4 laccA = f32x4{0.f, 0.f, 0.f, 0.f}, laccB = f32x4{0.f, 0.f, 0.f, 0.f};
  f32x4 oaccA[4], oaccB[4];
#pragma unroll
  for (int c = 0; c < 4; ++c) {
    oaccA[c] = f32x4{0.f, 0.f, 0.f, 0.f};
    oaccB[c] = f32x4{0.f, 0.f, 0.f, 0.f};
  }

  const int rbase = (lq >> 2) * 8 + (lq & 3);

  stage(0, t0);
  if (t0 + 1 < t1) stage(1, t0 + 1);
  int bi = 0;
  for (int t = t0; t < t1; ++t) {
    if (t + 1 < t1) WAIT_VM4; else WAIT_VM0;
    BARRIER;
    if (t + 2 < t1) {
      int nb = bi + 2; if (nb >= 3) nb -= 3;
      stage(nb, t + 2);
    }
    const unsigned short* Kb = Ks0 + bi * 4096;
    const unsigned short* Vb = Vs0 + bi * 4096;
    const int kk0 = t * 64;
    f32x4 saccA[4], saccB[4];
    __builtin_amdgcn_s_setprio(1);
#pragma unroll
    for (int c = 0; c < 4; ++c) {
      int row = rbase + 4 * (c & 1) + 32 * (c >> 1);
      int r7 = row & 7;
      U8 kf0, kf1;
      kf0.u = *(const u16x8*)&Kb[row * 64 + ((g ^ r7) * 8)];
      kf1.u = *(const u16x8*)&Kb[row * 64 + (((4 + g) ^ r7) * 8)];
      saccA[c] = __builtin_amdgcn_mfma_f32_16x16x32_bf16(kf0.b, aqA0.b,
                                                         f32x4{0.f, 0.f, 0.f, 0.f}, 0, 0, 0);
      saccA[c] = __builtin_amdgcn_mfma_f32_16x16x32_bf16(kf1.b, aqA1.b, saccA[c], 0, 0, 0);
      saccB[c] = __builtin_amdgcn_mfma_f32_16x16x32_bf16(kf0.b, aqB0.b,
                                                         f32x4{0.f, 0.f, 0.f, 0.f}, 0, 0, 0);
      saccB[c] = __builtin_amdgcn_mfma_f32_16x16x32_bf16(kf1.b, aqB1.b, saccB[c], 0, 0, 0);
    }
    __builtin_amdgcn_s_setprio(0);
    unsigned int pkA[4][2], pkB[4][2];
    if (t >= diag0) {
      ptile<true>(saccA, laccA, pkA, qrowA, kk0, g);
      ptile<true>(saccB, laccB, pkB, qrowB, kk0, g);
    } else {
      ptile<false>(saccA, laccA, pkA, qrowA, kk0, g);
      ptile<false>(saccB, laccB, pkB, qrowB, kk0, g);
    }
    __builtin_amdgcn_s_setprio(1);
#pragma unroll
    for (int hh = 0; hh < 2; ++hh) {
      PB pbA, pbB;
      pbA.w[0] = pkA[hh * 2 + 0][0]; pbA.w[1] = pkA[hh * 2 + 0][1];
      pbA.w[2] = pkA[hh * 2 + 1][0]; pbA.w[3] = pkA[hh * 2 + 1][1];
      pbB.w[0] = pkB[hh * 2 + 0][0]; pbB.w[1] = pkB[hh * 2 + 0][1];
      pbB.w[2] = pkB[hh * 2 + 1][0]; pbB.w[3] = pkB[hh * 2 + 1][1];
#pragma unroll
      for (int c = 0; c < 4; ++c) {
        U8 vf;
        vf.u = *(const u16x8*)&Vb[(c * 16 + lq) * 64 + (((hh * 4 + g) ^ (lq & 7)) * 8)];
        oaccA[c] = __builtin_amdgcn_mfma_f32_16x16x32_bf16(vf.b, pbA.b, oaccA[c], 0, 0, 0);
        oaccB[c] = __builtin_amdgcn_mfma_f32_16x16x32_bf16(vf.b, pbB.b, oaccB[c], 0, 0, 0);
      }
    }
    __builtin_amdgcn_s_setprio(0);
    ++bi; if (bi >= 3) bi = 0;
  }

  float lsA = (laccA[0] + laccA[1]) + (laccA[2] + laccA[3]);
  lsA += __shfl_xor(lsA, 16, 64);
  lsA += __shfl_xor(lsA, 32, 64);
  float lsB = (laccB[0] + laccB[1]) + (laccB[2] + laccB[3]);
  lsB += __shfl_xor(lsB, 16, 64);
  lsB += __shfl_xor(lsB, 32, 64);
  if (complete) {
    float invA = 1.0f / lsA, invB = 1.0f / lsB;
#pragma unroll
    for (int c = 0; c < 4; ++c) {
      u16x4 ovA, ovB;
#pragma unroll
      for (int r2 = 0; r2 < 4; ++r2) {
        ovA[r2] = f2bf(oaccA[c][r2] * invA);
        ovB[r2] = f2bf(oaccB[c][r2] * invB);
      }
      *(u16x4*)&O[((size_t)(b * 2048 + qrowA)) * 1024 + h * 64 + c * 16 + g * 4] = ovA;
      *(u16x4*)&O[((size_t)(b * 2048 + qrowB)) * 1024 + h * 64 + c * 16 + g * 4] = ovB;
    }
  } else {
    if (g == 0) {
      Lp[slot * 128 + lrowA] = lsA;
      Lp[slot * 128 + lrowB] = lsB;
    }
    size_t pbase = (size_t)slot * 8192;
#pragma unroll
    for (int c = 0; c < 4; ++c) {
      u16x4 ovA, ovB;
#pragma unroll
      for (int r2 = 0; r2 < 4; ++r2) {
        ovA[r2] = f2bf(oaccA[c][r2]);
        ovB[r2] = f2bf(oaccB[c][r2]);
      }
      *(u16x4*)&Pp[pbase + lrowA * 64 + c * 16 + g * 4] = ovA;
      *(u16x4*)&Pp[pbase + lrowB * 64 + c * 16 + g * 4] = ovB;
    }
  }
  WAIT_VM0;
  BARRIER;
}

__global__ __launch_bounds__(256) void k_flash(
    const unsigned short* __restrict__ Q, const unsigned short* __restrict__ Km,
    const unsigned short* __restrict__ Vt, unsigned short* __restrict__ O,
    unsigned short* __restrict__ Pp, float* __restrict__ Lp) {
  __shared__ unsigned short Ks[3 * 4096];
  __shared__ unsigned short Vs[3 * 4096];
  const int tid = threadIdx.x;
  const int lane = tid & 63, wid = tid >> 6;
  const int g = lane >> 4, lq = lane & 15;
  const int bid = blockIdx.x;               // 512 blocks
  const int xcd = bid & 7, idx = bid >> 3;  // 64 per XCD
  const int bh = xcd * 4 + (idx >> 4);      // 4 bh per XCD
  const int rr = idx & 15;
  const int p = rr >> 1, sp = rr & 1;
  const int mp = 15 - p;
  const int b = bh >> 4, h = bh & 15;
  const size_t qkbase = (size_t)bh * 2048 * 64;
  const size_t vbase = (size_t)bh * 64 * 2048;

  if (sp == 0) {
    flash_dual(true, p, 0, 2 * p + 2, 0, Q, Km, Vt, O, Pp, Lp,
               Ks, Vs, qkbase, vbase, b, h, tid, wid, g, lq);
    flash_dual(false, mp, 0, 15 - 2 * p, (bh * 8 + p) * 2 + 0, Q, Km, Vt, O, Pp, Lp,
               Ks, Vs, qkbase, vbase, b, h, tid, wid, g, lq);
  } else {
    flash_dual(false, mp, 15 - 2 * p, 32 - 2 * p, (bh * 8 + p) * 2 + 1, Q, Km, Vt, O, Pp, Lp,
               Ks, Vs, qkbase, vbase, b, h, tid, wid, g, lq);
  }
}

// ---------------- kernel 2b: combine mirror partials (128-row slots) ---------
__global__ __launch_bounds__(256) void k_combine(
    const unsigned short* __restrict__ Pp, const float* __restrict__ Lp,
    unsigned short* __restrict__ O) {
  int gid = blockIdx.x * 256 + threadIdx.x;   // 524288 threads
  int dv4 = gid & 15;
  int q   = (gid >> 4) & 127;
  int pi  = (gid >> 11) & 7;
  int bh  = gid >> 14;
  int slot0 = (bh * 8 + pi) * 2;
  size_t base = (size_t)slot0 * 8192 + q * 64 + dv4 * 4;
  u16x4 a = *(const u16x4*)&Pp[base];
  u16x4 c = *(const u16x4*)&Pp[base + 8192];
  float l = Lp[slot0 * 128 + q] + Lp[(slot0 + 1) * 128 + q];
  float inv = 1.0f / l;
  u16x4 o;
#pragma unroll
  for (int r = 0; r < 4; ++r) o[r] = f2bf((bf2f(a[r]) + bf2f(c[r])) * inv);
  int b = bh >> 4, h = bh & 15;
  int srow = (15 - pi) * 128 + q;
  *(u16x4*)&O[((size_t)(b * 2048 + srow)) * 1024 + h * 64 + dv4 * 4] = o;
}

// ---------------- launch ----------------
extern "C" void kernel_launch(void* const* d_in, const int* in_sizes, int n_in,
                              void* d_out, int out_size, void* d_ws, size_t ws_size,
                              hipStream_t stream) {
  const float* x  = (const float*)d_in[0];
  const float* Wq = (const float*)d_in[1];
  const float* bq = (const float*)d_in[2];
  const float* Wk = (const float*)d_in[3];
  const float* bk = (const float*)d_in[4];
  const float* Wv = (const float*)d_in[5];
  const float* bv = (const float*)d_in[6];
  const float* Wo = (const float*)d_in[7];
  const float* bo = (const float*)d_in[8];
  float* out = (float*)d_out;

  char* ws = (char*)d_ws;
  const size_t MB = 1024 * 1024;
  unsigned short* xb   = (unsigned short*)(ws + 0 * MB);   // 8 MB (dead after qkv)
  unsigned short* Wqt  = (unsigned short*)(ws + 8 * MB);   // 2 MB (dead after qkv)
  unsigned short* Wkt  = (unsigned short*)(ws + 10 * MB);  // 2 MB
  unsigned short* Wvt  = (unsigned short*)(ws + 12 * MB);  // 2 MB
  unsigned short* Wot  = (unsigned short*)(ws + 14 * MB);  // 2 MB (used by out-proj)
  unsigned short* Qws  = (unsigned short*)(ws + 16 * MB);  // 8 MB
  unsigned short* Kws  = (unsigned short*)(ws + 24 * MB);  // 8 MB
  unsigned short* Vtws = (unsigned short*)(ws + 32 * MB);  // 8 MB
  unsigned short* Ows  = (unsigned short*)(ws + 40 * MB);  // 8 MB
  unsigned short* Pp   = (unsigned short*)(ws + 0 * MB);   // 8 MB, overlays xb
  float*          Lp   = (float*)(ws + 8 * MB);            // 256 KB, overlays Wqt

  k_prep<<<dim3(32, 32, 8), dim3(32, 8), 0, stream>>>(Wq, Wk, Wv, Wo,
                                                      Wqt, Wkt, Wvt, Wot, x, xb);
  k_gemm_qkv<<<dim3(32, 8, 3), 256, 0, stream>>>(xb, Wqt, Wkt, Wvt, bq, bk, bv,
                                                 Qws, Kws, Vtws);
  k_flash<<<512, 256, 0, stream>>>(Qws, Kws, Vtws, Ows, Pp, Lp);
  k_combine<<<2048, 256, 0, stream>>>(Pp, Lp, Ows);
  k_gemm_out<<<dim3(32, 8), 256, 0, stream>>>(Ows, Wot, bo, out);
}